// Round 2
// baseline (13967.227 us; speedup 1.0000x reference)
//
#include <hip/hip_runtime.h>
#include <stdint.h>

#define B 64
#define V 32000
#define E 512
#define H 1024
#define T_STEPS 64
#define FLT_TINY 1.1754943508222875e-38f

// ---------------- threefry2x32-20, bit-exact vs JAX/random123 ----------------
__device__ __forceinline__ uint32_t rotl32(uint32_t x, int r) {
  return (x << r) | (x >> (32 - r));
}

__device__ __forceinline__ void threefry(uint32_t k0, uint32_t k1,
                                         uint32_t x0, uint32_t x1,
                                         uint32_t& o0, uint32_t& o1) {
  uint32_t k2 = k0 ^ k1 ^ 0x1BD11BDAu;
  x0 += k0; x1 += k1;
#define TF_RND(r) { x0 += x1; x1 = rotl32(x1, (r)); x1 ^= x0; }
  TF_RND(13) TF_RND(15) TF_RND(26) TF_RND(6)
  x0 += k1; x1 += k2 + 1u;
  TF_RND(17) TF_RND(29) TF_RND(16) TF_RND(24)
  x0 += k2; x1 += k0 + 2u;
  TF_RND(13) TF_RND(15) TF_RND(26) TF_RND(6)
  x0 += k0; x1 += k1 + 3u;
  TF_RND(17) TF_RND(29) TF_RND(16) TF_RND(24)
  x0 += k1; x1 += k2 + 4u;
  TF_RND(13) TF_RND(15) TF_RND(26) TF_RND(6)
  x0 += k2; x1 += k0 + 5u;
#undef TF_RND
  o0 = x0; o1 = x1;
}

__device__ __forceinline__ float gumbel_from_bits(uint32_t bits) {
  // JAX uniform: bitcast(bits>>9 | 0x3f800000) - 1.0, then max(FLT_MIN, .)
  float f = __uint_as_float((bits >> 9) | 0x3f800000u) - 1.0f;
  float u = fmaxf(f, FLT_TINY);
  return -logf(-logf(u));
}

// ---------------- init: h0 = concat(init_hidden, att), x0 = emb[inputs], split keys ----------------
__global__ void k_init(const int* __restrict__ inputs,
                       const float* __restrict__ init_h,
                       const float* __restrict__ att,
                       const float* __restrict__ emb,
                       float* __restrict__ hT, float* __restrict__ xT,
                       uint32_t* __restrict__ keys) {
  int b = blockIdx.x;
  int tid = threadIdx.x;
  for (int j = tid; j < H; j += 256) {
    float v = (j < 768) ? init_h[b * 768 + j] : att[b * 256 + (j - 768)];
    hT[j * B + b] = v;
  }
  int s = inputs[b];
  for (int k = tid; k < E; k += 256) xT[k * B + b] = emb[(size_t)s * E + k];
  if (b == 0 && tid < 64) {
    // partitionable split: key_t = threefry(key, hi=0, lo=t), both output words
    uint32_t o0, o1;
    threefry(0u, 42u, 0u, (uint32_t)tid, o0, o1);
    keys[2 * tid] = o0;
    keys[2 * tid + 1] = o1;
  }
}

// ---------------- GRU gate GEMMs: gi = x@W_ih^T, gh = h@W_hh^T (fp32 exact) ----------------
// grid 768 x 256 : one thread per (m, b), m in [0,3072)
__global__ void k_gates(const float* __restrict__ xT, const float* __restrict__ hT,
                        const float* __restrict__ W_ih, const float* __restrict__ W_hh,
                        const float* __restrict__ b_ih, const float* __restrict__ b_hh,
                        float* __restrict__ Grz, float* __restrict__ Gin,
                        float* __restrict__ Ghn) {
  int gid = blockIdx.x * 256 + threadIdx.x;
  int m = gid >> 6;        // wave-uniform (lanes share m)
  int b = gid & 63;
  const float4* wi = (const float4*)(W_ih + (size_t)m * E);
  float gi = 0.f;
  #pragma unroll 4
  for (int k4 = 0; k4 < E / 4; ++k4) {
    float4 w = wi[k4];
    int k = k4 * 4;
    gi += w.x * xT[k * B + b] + w.y * xT[(k + 1) * B + b]
        + w.z * xT[(k + 2) * B + b] + w.w * xT[(k + 3) * B + b];
  }
  const float4* wh = (const float4*)(W_hh + (size_t)m * H);
  float gh = 0.f;
  #pragma unroll 4
  for (int k4 = 0; k4 < H / 4; ++k4) {
    float4 w = wh[k4];
    int k = k4 * 4;
    gh += w.x * hT[k * B + b] + w.y * hT[(k + 1) * B + b]
        + w.z * hT[(k + 2) * B + b] + w.w * hT[(k + 3) * B + b];
  }
  if (m < 2 * H) {
    Grz[m * B + b] = gi + gh + b_ih[m] + b_hh[m];   // r and z gates: pre-activation sum
  } else {
    int j = m - 2 * H;
    Gin[j * B + b] = gi + b_ih[m];                  // n gate needs gi/gh separate (r*h_n)
    Ghn[j * B + b] = gh + b_hh[m];
  }
}

// ---------------- GRU elementwise update ----------------
__global__ void k_hnew(const float* __restrict__ Grz, const float* __restrict__ Gin,
                       const float* __restrict__ Ghn, const float* __restrict__ hcur,
                       float* __restrict__ hnext) {
  int gid = blockIdx.x * 256 + threadIdx.x;   // 65536 = H*B
  int j = gid >> 6, b = gid & 63;
  float r = 1.f / (1.f + expf(-Grz[j * B + b]));
  float z = 1.f / (1.f + expf(-Grz[(H + j) * B + b]));
  float n = tanhf(Gin[j * B + b] + r * Ghn[j * B + b]);
  hnext[j * B + b] = (1.f - z) * n + z * hcur[j * B + b];
}

// ---------------- logits GEMM: out[t*B+b][c] = h_new . W_out[c] + b_out[c]  (fp32, LDS-tiled) ----------------
// grid 500 x 256, 64x64 output tile per block
__global__ void k_logits(const float* __restrict__ hT, const float* __restrict__ W_out,
                         const float* __restrict__ b_out, float* __restrict__ out, int t) {
  __shared__ float Hs[64][65];   // [k][b]
  __shared__ float Ws[64][65];   // [c][k]
  int tid = threadIdx.x;
  int c0 = blockIdx.x * 64;
  float acc[4][4] = {{0.f}};
  int bq = (tid & 15) * 4;
  int cq = (tid >> 4) * 4;
  for (int kt = 0; kt < H / 64; ++kt) {
    int k0 = kt * 64;
    #pragma unroll
    for (int i = 0; i < 16; ++i) {
      int kl = (tid >> 6) + i * 4;
      int bb = tid & 63;
      Hs[kl][bb] = hT[(k0 + kl) * B + bb];
      int ci = (tid >> 6) + i * 4;
      Ws[ci][tid & 63] = W_out[(size_t)(c0 + ci) * H + k0 + (tid & 63)];
    }
    __syncthreads();
    #pragma unroll 8
    for (int k = 0; k < 64; ++k) {
      float a0 = Hs[k][bq], a1 = Hs[k][bq + 1], a2 = Hs[k][bq + 2], a3 = Hs[k][bq + 3];
      float w0 = Ws[cq][k], w1 = Ws[cq + 1][k], w2 = Ws[cq + 2][k], w3 = Ws[cq + 3][k];
      acc[0][0] += a0 * w0; acc[0][1] += a0 * w1; acc[0][2] += a0 * w2; acc[0][3] += a0 * w3;
      acc[1][0] += a1 * w0; acc[1][1] += a1 * w1; acc[1][2] += a1 * w2; acc[1][3] += a1 * w3;
      acc[2][0] += a2 * w0; acc[2][1] += a2 * w1; acc[2][2] += a2 * w2; acc[2][3] += a2 * w3;
      acc[3][0] += a3 * w0; acc[3][1] += a3 * w1; acc[3][2] += a3 * w2; acc[3][3] += a3 * w3;
    }
    __syncthreads();
  }
  #pragma unroll
  for (int i = 0; i < 4; ++i)
    #pragma unroll
    for (int j = 0; j < 4; ++j) {
      int bb = bq + i, c = c0 + cq + j;
      out[((size_t)(t * B + bb)) * V + c] = acc[i][j] + b_out[c];
    }
}

// ---------------- categorical sample (partitionable threefry+gumbel) + embedding gather ----------------
// grid B x 256, one block per row
__global__ void k_sample(const float* __restrict__ out, const uint32_t* __restrict__ keys,
                         const float* __restrict__ emb, float* __restrict__ xT,
                         float* __restrict__ out_ids, int t) {
  __shared__ float sval[256];
  __shared__ int sidx[256];
  __shared__ int s_sid;
  int b = blockIdx.x, tid = threadIdx.x;
  uint32_t k0 = keys[2 * t], k1 = keys[2 * t + 1];
  const float* lrow = out + ((size_t)(t * B + b)) * V;
  float best = -3.0e38f;
  int bidx = 0;
  for (int v = tid; v < V; v += 256) {
    // partitionable random_bits: bits[f] = o0 ^ o1 of threefry(key, hi=0, lo=f)
    uint32_t f = (uint32_t)(b * V + v);
    uint32_t o0, o1;
    threefry(k0, k1, 0u, f, o0, o1);
    uint32_t bits = o0 ^ o1;
    float val = lrow[v] + gumbel_from_bits(bits);
    if (val > best) { best = val; bidx = v; }   // strict >: first-occurrence tie rule
  }
  sval[tid] = best; sidx[tid] = bidx;
  __syncthreads();
  for (int s = 128; s > 0; s >>= 1) {
    if (tid < s) {
      float ov = sval[tid + s]; int oi = sidx[tid + s];
      if (ov > sval[tid] || (ov == sval[tid] && oi < sidx[tid])) { sval[tid] = ov; sidx[tid] = oi; }
    }
    __syncthreads();
  }
  if (tid == 0) {
    s_sid = sidx[0];
    out_ids[b * T_STEPS + t] = (float)sidx[0];   // ids stored as float32 values
  }
  __syncthreads();
  int sid = s_sid;
  for (int k = tid; k < E; k += 256) xT[k * B + b] = emb[(size_t)sid * E + k];
}

extern "C" void kernel_launch(void* const* d_in, const int* in_sizes, int n_in,
                              void* d_out, int out_size, void* d_ws, size_t ws_size,
                              hipStream_t stream) {
  const int*   inputs = (const int*)d_in[0];
  // d_in[1] = max_length (constant 64)
  const float* init_h = (const float*)d_in[2];
  const float* att    = (const float*)d_in[3];
  const float* emb    = (const float*)d_in[4];
  const float* W_ih   = (const float*)d_in[5];
  const float* W_hh   = (const float*)d_in[6];
  const float* b_ih   = (const float*)d_in[7];
  const float* b_hh   = (const float*)d_in[8];
  const float* W_out  = (const float*)d_in[9];
  const float* b_out  = (const float*)d_in[10];

  float* out = (float*)d_out;
  float* out_ids = out + (size_t)T_STEPS * B * V;

  char* wsp = (char*)d_ws;
  float* hT0 = (float*)wsp; wsp += (size_t)H * B * 4;
  float* hT1 = (float*)wsp; wsp += (size_t)H * B * 4;
  float* xT  = (float*)wsp; wsp += (size_t)E * B * 4;
  float* Grz = (float*)wsp; wsp += (size_t)2 * H * B * 4;
  float* Gin = (float*)wsp; wsp += (size_t)H * B * 4;
  float* Ghn = (float*)wsp; wsp += (size_t)H * B * 4;
  uint32_t* keys = (uint32_t*)wsp; wsp += 128 * 4;

  k_init<<<B, 256, 0, stream>>>(inputs, init_h, att, emb, hT0, xT, keys);

  float* hcur = hT0;
  float* hnext = hT1;
  for (int t = 0; t < T_STEPS; ++t) {
    k_gates<<<768, 256, 0, stream>>>(xT, hcur, W_ih, W_hh, b_ih, b_hh, Grz, Gin, Ghn);
    k_hnew<<<256, 256, 0, stream>>>(Grz, Gin, Ghn, hcur, hnext);
    k_logits<<<V / 64, 256, 0, stream>>>(hnext, W_out, b_out, out, t);
    k_sample<<<B, 256, 0, stream>>>(out, keys, emb, xT, out_ids, t);
    float* tmp = hcur; hcur = hnext; hnext = tmp;
  }
}